// Round 9
// baseline (215.447 us; speedup 1.0000x reference)
//
#include <hip/hip_runtime.h>
#include <float.h>

// PQHead forward: out[b, m*6+d] = codebooks[m, argmax_k dot(x[b,m,:], cb[m,k,:]), d]
// (straight-through estimator: forward value of quant is exactly `discrete`)
//
// R15: single-wave blocks — probe/fix the residency quantum.
//  - R14 post-mortem: TA ~4 lines/cy/CU (measured via prologue fix: modeled
//    30us @1line/cy, got 7.8us) -> TA no longer the bottleneck.
//  - Invariant: ~650 half-rows/us chip throughput and ~30% occupancy across
//    ALL schedules (R6/R7/R10/R13/R14) with no static residency cap.
//    Waves issue VALU ~17% of lifetime -> TLP-starved.
//  - Hypothesis: the 4-wave gang (256-thr block) is the residency/launch
//    quantum (SPI co-allocation + gang-coupled stalls) and sets the
//    equilibrium. Fix: 64-thread blocks (1 wave), BROWS=8, grid
//    (4096, 2, 4) = 32768 blocks; LDS 3 KB; __syncthreads degenerates to
//    waitcnt (zero inter-wave coupling). Sweep shape preserved: in-order
//    bx within 8 disjoint column-planes, no x duplication.
//  - cw workspace layout UNCHANGED from R14 (group g = mhalf*4 + mg).
//  - Select (R9/R10): pk-max tree + DPP quad-max + eps-mask; popcount==1
//    -> ctz; else quad-uniform exact fp64 fallback. Phases B/C proven.
//  - TRIPWIRES: WRITE 98304 KB exactly; FETCH <= 55 MB; VGPR <= 64.

typedef float v2f __attribute__((ext_vector_type(2)));

#define BATCH 32768
#define DIM   768
#define K_CB  32
#define D_SUB 6
#define BROWS 8                // rows per block
#define HALFF 384              // floats per half row (64 m * 6)
#define SLICE 96               // floats per row slice (16 m * 6)
#define STGF  (BROWS*SLICE)    // 768 floats = 3 KiB
#define EPS_TIE 1e-5f
#define CW_PIECES 6144         // 8 groups * 12 instr * 64 lanes (float4 units)
#define CW_BYTES  (CW_PIECES*16)

#define DPP_XOR1 0xB1          // quad_perm [1,0,3,2]
#define DPP_XOR2 0x4E          // quad_perm [2,3,0,1]

template<int CTRL>
__device__ __forceinline__ float dppf(float v) {
    return __int_as_float(__builtin_amdgcn_update_dpp(
        0, __float_as_int(v), CTRL, 0xF, 0xF, true));
}
template<int CTRL>
__device__ __forceinline__ int dppi(int v) {
    return __builtin_amdgcn_update_dpp(0, v, CTRL, 0xF, 0xF, true);
}

// Async global->LDS, 16 B per lane. size must be a literal constant.
__device__ __forceinline__ void glds16(const float* g, float* l) {
    __builtin_amdgcn_global_load_lds(
        (const __attribute__((address_space(1))) void*)g,
        (__attribute__((address_space(3))) void*)l,
        16, 0, 0);
}

// Rearrange cb (128*32*6 fp32 = 96 KiB) into wave-load order:
// cw[g*768 + i*64 + l] = float4 at cb[m*192 + kq*48 + 4i], where
// m = (g>>2)*64 + (g&3)*16 + (l>>2), kq = l&3.   (identical to R14)
__global__ void pq_prep(const float* __restrict__ cb,
                        float4* __restrict__ cw) {
    int P = blockIdx.x * 256 + threadIdx.x;   // 0..6143
    if (P >= CW_PIECES) return;
    int g = P / 768;
    int q = P - g * 768;
    int i = q >> 6;
    int l = q & 63;
    int m  = (g >> 2) * 64 + (g & 3) * 16 + (l >> 2);
    int kq = l & 3;
    cw[P] = *reinterpret_cast<const float4*>(cb + m * 192 + kq * 48 + 4 * i);
}

template<int USE_WS>
__global__ __launch_bounds__(64, 4)
void pq_head_kernel(const float* __restrict__ x,
                    const float* __restrict__ cb,
                    const float4* __restrict__ cw,
                    float* __restrict__ out) {
    __shared__ float xs[STGF];      // 3 KiB, single wave's 8 row-slices

    const int t     = threadIdx.x;  // 0..63
    const int kq    = t & 3;        // k-quarter (lane within quad)
    const int mq    = t >> 2;       // 0..15 (quad id = m within slice)
    const int mhalf = blockIdx.y;   // 0/1
    const int mg    = blockIdx.z;   // 0..3 (16-m group within half)
    const int m     = mhalf * 64 + mg * 16 + mq;
    const int b0    = blockIdx.x * BROWS;

    const float* xh = x   + (size_t)mhalf * HALFF + mg * SLICE;
    float*       oh = out + (size_t)mhalf * HALFF + mg * SLICE;

    // Issue the x stage FIRST (3 x 16B/lane = 3 KiB); latency overlaps the
    // cb prologue. LDS dest linear in lane -> matches glds HW rule.
    #pragma unroll
    for (int i = 0; i < 3; ++i) {
        int f = (i * 64 + t) * 4;           // float index within stage (<768)
        int r = f / SLICE;
        int c = f - r * SLICE;
        glds16(xh + (size_t)(b0 + r) * DIM + c, &xs[f]);
    }

    // Load this lane's 8 codebook rows (48 floats) and pack code-pairs
    // into v2f: cpk[p][e] = (cb[2p][e], cb[2p+1][e]).
    v2f cpk[4][D_SUB];
    {
        float cc[48];
        if constexpr (USE_WS) {
            // Wave-load-order: instr i reads 64 consecutive float4s
            // (16 lines/instr). Group g = mhalf*4 + mg, lane l = t.
            const float4* wp = cw + ((size_t)mhalf * 4 + mg) * 768 + t;
            #pragma unroll
            for (int i = 0; i < 12; ++i) {
                float4 v = wp[i * 64];
                cc[4*i+0]=v.x; cc[4*i+1]=v.y; cc[4*i+2]=v.z; cc[4*i+3]=v.w;
            }
        } else {
            const float4* cb4 = reinterpret_cast<const float4*>(
                cb + ((size_t)m * K_CB + (size_t)kq * 8) * D_SUB);
            #pragma unroll
            for (int i = 0; i < 12; ++i) {
                float4 v = cb4[i];
                cc[4*i+0]=v.x; cc[4*i+1]=v.y; cc[4*i+2]=v.z; cc[4*i+3]=v.w;
            }
        }
        #pragma unroll
        for (int p = 0; p < 4; ++p)
            #pragma unroll
            for (int e = 0; e < D_SUB; ++e)
                cpk[p][e] = (v2f){cc[(2*p)*D_SUB + e], cc[(2*p+1)*D_SUB + e]};
    }

    __syncthreads();   // 1-wave block: compiles to waitcnt drain, no gang stall

    // ---- phase A: 8 winner computations -> kg8[] ----
    int kg8[BROWS];
    #pragma unroll
    for (int r = 0; r < BROWS; ++r) {
        const float* xr = &xs[r * SLICE + mq * D_SUB];     // quad-broadcast
        float2 x01 = *reinterpret_cast<const float2*>(xr);
        float2 x23 = *reinterpret_cast<const float2*>(xr + 2);
        float2 x45 = *reinterpret_cast<const float2*>(xr + 4);
        float xv[6] = {x01.x, x01.y, x23.x, x23.y, x45.x, x45.y};
        v2f xxe[6];
        #pragma unroll
        for (int e = 0; e < 6; ++e) xxe[e] = (v2f){xv[e], xv[e]};

        // 8 packed dots, kept live in acc[4].
        v2f acc[4];
        #pragma unroll
        for (int p = 0; p < 4; ++p) {
            v2f a = cpk[p][0] * xxe[0];
            #pragma unroll
            for (int e = 1; e < 6; ++e)
                a = __builtin_elementwise_fma(cpk[p][e], xxe[e], a);
            acc[p] = a;
        }

        // Quad max via pk-max tree + 2 DPP merges (pure VALU, ~8 ops).
        v2f t0 = __builtin_elementwise_max(acc[0], acc[1]);
        v2f t1 = __builtin_elementwise_max(acc[2], acc[3]);
        v2f t2 = __builtin_elementwise_max(t0, t1);
        float best1 = fmaxf(t2.x, t2.y);
        best1 = fmaxf(best1, dppf<DPP_XOR1>(best1));
        best1 = fmaxf(best1, dppf<DPP_XOR2>(best1));

        // Epsilon-match mask: bit j set iff dot_j > best1 - 1e-5.
        const float thr = best1 - EPS_TIE;
        int msk = 0;
        #pragma unroll
        for (int p = 0; p < 4; ++p) {
            if (acc[p].x > thr) msk |= 1 << (2*p);
            if (acc[p].y > thr) msk |= 1 << (2*p+1);
        }
        int full = msk << (kq * 8);
        full |= dppi<DPP_XOR1>(full);
        full |= dppi<DPP_XOR2>(full);   // quad-uniform 32-bit mask

        int kg;
        if (__builtin_popcount(full) == 1) {
            // Unique near-max => it IS the strict argmax.
            kg = __builtin_ctz(full);
        } else {
            // Ambiguous within 1e-5 (incl. exact ties): exact fp64 argmax,
            // first-wins — matches jnp.argmax. Quad-uniform branch.
            const float* crow = cb + (size_t)m * K_CB * D_SUB;
            double db = -1e300; int dkg = 0;
            for (int k2 = 0; k2 < K_CB; ++k2) {
                double sa = 0.0;
                for (int e = 0; e < 6; ++e)
                    sa = fma((double)crow[k2*6+e], (double)xv[e], sa);
                if (sa > db) { db = sa; dkg = k2; }
            }
            kg = dkg;
        }
        kg8[r] = kg;
    }

    // ---- phase B: 8 independent winner gathers (cb is L1/L2-hot) ----
    const bool act = (kq < 3);
    float2 gv[BROWS];
    if (act) {
        #pragma unroll
        for (int r = 0; r < BROWS; ++r)
            gv[r] = *(reinterpret_cast<const float2*>(
                cb + ((size_t)m * K_CB + (size_t)kg8[r]) * D_SUB) + kq);
    }

    __builtin_amdgcn_sched_barrier(0);  // keep all gathers above all stores

    // ---- phase C: 8 coalesced float2 stores (12 quads -> 384 B = 6 lines) ----
    if (act) {
        #pragma unroll
        for (int r = 0; r < BROWS; ++r) {
            float* dst = oh + (size_t)(b0 + r) * DIM + mq * D_SUB;
            *(reinterpret_cast<float2*>(dst) + kq) = gv[r];
        }
    }
}

extern "C" void kernel_launch(void* const* d_in, const int* in_sizes, int n_in,
                              void* d_out, int out_size, void* d_ws, size_t ws_size,
                              hipStream_t stream) {
    const float* x  = (const float*)d_in[0];   // (32768, 768) fp32
    const float* cb = (const float*)d_in[1];   // (128, 32, 6) fp32
    float* out = (float*)d_out;                // (32768, 768) fp32

    dim3 grid(BATCH / BROWS, 2, 4);  // 4096 x 2 x 4 = 32768 single-wave blocks
    dim3 block(64);                  // 16 m-quads x 4 k-quarters

    if (ws_size >= (size_t)CW_BYTES) {
        float4* cw = (float4*)d_ws;
        hipLaunchKernelGGL(pq_prep, dim3(CW_PIECES / 256), dim3(256), 0, stream,
                           cb, cw);
        hipLaunchKernelGGL(pq_head_kernel<1>, grid, block, 0, stream,
                           x, cb, cw, out);
    } else {
        hipLaunchKernelGGL(pq_head_kernel<0>, grid, block, 0, stream,
                           x, cb, (const float4*)nullptr, out);
    }
}